// Round 1
// baseline (1716.275 us; speedup 1.0000x reference)
//
#include <hip/hip_runtime.h>
#include <hip/hip_bf16.h>

#define B_   4
#define C_   512
#define C8_  64
#define HW_  4096
#define NT   32      // queries per flash block
#define MT   256     // keys per inner tile
#define NTILES (HW_ / MT)

__device__ __forceinline__ float bf2f(unsigned short u) {
  union { unsigned int i; float f; } x; x.i = ((unsigned int)u) << 16; return x.f;
}
__device__ __forceinline__ unsigned short f2bf(float f) {
  union { unsigned int i; float f; } x; x.f = f;
  unsigned int r = x.i + 0x7fffu + ((x.i >> 16) & 1u);   // RNE
  return (unsigned short)(r >> 16);
}

// ---------------------------------------------------------------------------
// proj_t: Out[b][m][o] = sum_ci X[b][ci][m] * W[o][ci] + bias[o]
// (transposed store; used for Q (fp32, OC=64) and V (bf16, OC=512))
// grid: (HW/64, OC/64, B), block 256
// ---------------------------------------------------------------------------
template <bool BF16OUT>
__global__ __launch_bounds__(256) void proj_t_kernel(
    const float* __restrict__ X, const float* __restrict__ W,
    const float* __restrict__ bias, void* __restrict__ Out, int OC) {
  __shared__ __align__(16) float Xs[8][64];
  __shared__ __align__(16) float Ws[8][64];
  const int t  = threadIdx.x;
  const int b  = blockIdx.z;
  const int m0 = blockIdx.x * 64;
  const int o0 = blockIdx.y * 64;
  const int tx = t & 15;   // o quad
  const int ty = t >> 4;   // m quad
  float acc[4][4] = {};    // [m][o]
  const float* Xb = X + (size_t)b * C_ * HW_;

  for (int c0 = 0; c0 < C_; c0 += 8) {
    {
      int e = t, kk = e >> 6, mm = e & 63;
      Xs[kk][mm] = Xb[(size_t)(c0 + kk) * HW_ + m0 + mm];
      e = t + 256; kk = e >> 6; mm = e & 63;
      Xs[kk][mm] = Xb[(size_t)(c0 + kk) * HW_ + m0 + mm];
      e = t; int oo = e >> 3, k2 = e & 7;
      Ws[k2][oo] = W[(size_t)(o0 + oo) * C_ + c0 + k2];
      e = t + 256; oo = e >> 3; k2 = e & 7;
      Ws[k2][oo] = W[(size_t)(o0 + oo) * C_ + c0 + k2];
    }
    __syncthreads();
#pragma unroll
    for (int kk = 0; kk < 8; ++kk) {
      const float4 xv = *(const float4*)&Xs[kk][ty * 4];
      const float4 wv = *(const float4*)&Ws[kk][tx * 4];
      const float xa[4] = {xv.x, xv.y, xv.z, xv.w};
      const float wa[4] = {wv.x, wv.y, wv.z, wv.w};
#pragma unroll
      for (int i = 0; i < 4; ++i)
#pragma unroll
        for (int j = 0; j < 4; ++j) acc[i][j] += xa[i] * wa[j];
    }
    __syncthreads();
  }

  float bj[4];
#pragma unroll
  for (int j = 0; j < 4; ++j) bj[j] = bias[o0 + tx * 4 + j];

  if (BF16OUT) {
    unsigned short* Ob = (unsigned short*)Out + (size_t)b * HW_ * OC;
#pragma unroll
    for (int i = 0; i < 4; ++i) {
      ushort4 r;
      r.x = f2bf(acc[i][0] + bj[0]); r.y = f2bf(acc[i][1] + bj[1]);
      r.z = f2bf(acc[i][2] + bj[2]); r.w = f2bf(acc[i][3] + bj[3]);
      *(ushort4*)&Ob[(size_t)(m0 + ty * 4 + i) * OC + o0 + tx * 4] = r;
    }
  } else {
    float* Ob = (float*)Out + (size_t)b * HW_ * OC;
#pragma unroll
    for (int i = 0; i < 4; ++i) {
      float4 r = make_float4(acc[i][0] + bj[0], acc[i][1] + bj[1],
                             acc[i][2] + bj[2], acc[i][3] + bj[3]);
      *(float4*)&Ob[(size_t)(m0 + ty * 4 + i) * OC + o0 + tx * 4] = r;
    }
  }
}

// ---------------------------------------------------------------------------
// proj_k: Out[b][o][m] = sum_ci X[b][ci][m]*Wk[o][ci] + bk[o] + ht[o][h] + wt[o][w]
// grid: (HW/64, B), block 256   (m-tile == one image row h)
// ---------------------------------------------------------------------------
__global__ __launch_bounds__(256) void proj_k_kernel(
    const float* __restrict__ X, const float* __restrict__ W,
    const float* __restrict__ bias, const float* __restrict__ ht,
    const float* __restrict__ wt, float* __restrict__ Out) {
  __shared__ __align__(16) float Xs[8][64];
  __shared__ __align__(16) float Ws[8][64];
  const int t  = threadIdx.x;
  const int b  = blockIdx.y;
  const int m0 = blockIdx.x * 64;
  const int tx = t & 15;   // m quad
  const int ty = t >> 4;   // o quad
  float acc[4][4] = {};    // [o][m]
  const float* Xb = X + (size_t)b * C_ * HW_;

  for (int c0 = 0; c0 < C_; c0 += 8) {
    {
      int e = t, kk = e >> 6, mm = e & 63;
      Xs[kk][mm] = Xb[(size_t)(c0 + kk) * HW_ + m0 + mm];
      e = t + 256; kk = e >> 6; mm = e & 63;
      Xs[kk][mm] = Xb[(size_t)(c0 + kk) * HW_ + m0 + mm];
      e = t; int oo = e >> 3, k2 = e & 7;
      Ws[k2][oo] = W[(size_t)oo * C_ + c0 + k2];
      e = t + 256; oo = e >> 3; k2 = e & 7;
      Ws[k2][oo] = W[(size_t)oo * C_ + c0 + k2];
    }
    __syncthreads();
#pragma unroll
    for (int kk = 0; kk < 8; ++kk) {
      const float4 wv = *(const float4*)&Ws[kk][ty * 4];
      const float4 xv = *(const float4*)&Xs[kk][tx * 4];
      const float wa[4] = {wv.x, wv.y, wv.z, wv.w};
      const float xa[4] = {xv.x, xv.y, xv.z, xv.w};
#pragma unroll
      for (int i = 0; i < 4; ++i)
#pragma unroll
        for (int j = 0; j < 4; ++j) acc[i][j] += wa[i] * xa[j];
    }
    __syncthreads();
  }

  const int h = blockIdx.x;  // m-tile is one full row
#pragma unroll
  for (int oo = 0; oo < 4; ++oo) {
    const int o = ty * 4 + oo;
    const float base = bias[o] + ht[o * 64 + h];
    float4 r;
    r.x = acc[oo][0] + base + wt[o * 64 + tx * 4 + 0];
    r.y = acc[oo][1] + base + wt[o * 64 + tx * 4 + 1];
    r.z = acc[oo][2] + base + wt[o * 64 + tx * 4 + 2];
    r.w = acc[oo][3] + base + wt[o * 64 + tx * 4 + 3];
    *(float4*)&Out[((size_t)b * C8_ + o) * HW_ + m0 + tx * 4] = r;
  }
}

// ---------------------------------------------------------------------------
// flash attention: per block (b, 32 queries), online softmax over 16 key tiles
// ---------------------------------------------------------------------------
__global__ __launch_bounds__(256) void flash_kernel(
    const float* __restrict__ Qt,            // [B][HW][64]
    const float* __restrict__ Kp,            // [B][64][HW]  (k + bias + pos)
    const unsigned short* __restrict__ Vt,   // [B][HW][512] bf16
    const float* __restrict__ fe,            // [B][C][HW]
    const float* __restrict__ gamma,
    float* __restrict__ out) {
  __shared__ __align__(16) float Qs[64][36];    // [c][j], pad 36 for b128 reads
  __shared__ __align__(16) float Es[MT][36];    // [mm][j]
  __shared__ float M_s[NT], A_s[NT], S_s[NT], red_s[NT];

  const int t  = threadIdx.x;
  const int b  = blockIdx.y;
  const int n0 = blockIdx.x * NT;

  // load Q tile (32 x 64) transposed into Qs[c][j]
  const float* Qb = Qt + ((size_t)b * HW_ + n0) * C8_;
#pragma unroll
  for (int i = 0; i < 8; ++i) {
    int e = t + i * 256;
    int j = e >> 6, c = e & 63;
    Qs[c][j] = Qb[(size_t)j * C8_ + c];
  }
  if (t < NT) { M_s[t] = -3.0e38f; S_s[t] = 0.0f; }
  float acc0[NT] = {};   // channel c0 = t
  float acc1[NT] = {};   // channel c1 = t + 256
  __syncthreads();

  const float* Kb = Kp + (size_t)b * C8_ * HW_;
  const unsigned short* Vb = Vt + (size_t)b * HW_ * C_;

  for (int tile = 0; tile < NTILES; ++tile) {
    const int m0 = tile * MT;

    // ---- E[j][t] = sum_c Qs[c][j] * K[c][m0+t] ----
    float e[NT] = {};
    const float* kp = Kb + m0 + t;
#pragma unroll 2
    for (int c = 0; c < C8_; ++c) {
      const float kv = kp[(size_t)c * HW_];
#pragma unroll
      for (int jj = 0; jj < NT / 4; ++jj) {
        const float4 q4 = *(const float4*)&Qs[c][jj * 4];
        e[jj * 4 + 0] += q4.x * kv; e[jj * 4 + 1] += q4.y * kv;
        e[jj * 4 + 2] += q4.z * kv; e[jj * 4 + 3] += q4.w * kv;
      }
    }
#pragma unroll
    for (int jj = 0; jj < NT / 4; ++jj)
      *(float4*)&Es[t][jj * 4] =
          make_float4(e[jj * 4], e[jj * 4 + 1], e[jj * 4 + 2], e[jj * 4 + 3]);
    __syncthreads();

    // ---- per-row max over the tile ----
    {
      const int l = t & 7, j = t >> 3;
      float p = -3.0e38f;
#pragma unroll 8
      for (int i = 0; i < MT / 8; ++i) p = fmaxf(p, Es[l + i * 8][j]);
      p = fmaxf(p, __shfl_down(p, 4, 8));
      p = fmaxf(p, __shfl_down(p, 2, 8));
      p = fmaxf(p, __shfl_down(p, 1, 8));
      if (l == 0) red_s[j] = p;
    }
    __syncthreads();
    if (t < NT) {
      const float mo = M_s[t];
      const float mn = fmaxf(mo, red_s[t]);
      M_s[t] = mn;
      A_s[t] = __expf(mo - mn);
    }
    __syncthreads();

    // ---- P = exp(E - M); rescale accumulators ----
#pragma unroll
    for (int jj = 0; jj < NT / 4; ++jj) {
      float4 ev = *(float4*)&Es[t][jj * 4];
      ev.x = __expf(ev.x - M_s[jj * 4 + 0]);
      ev.y = __expf(ev.y - M_s[jj * 4 + 1]);
      ev.z = __expf(ev.z - M_s[jj * 4 + 2]);
      ev.w = __expf(ev.w - M_s[jj * 4 + 3]);
      *(float4*)&Es[t][jj * 4] = ev;
    }
#pragma unroll
    for (int j = 0; j < NT; ++j) {
      const float a = A_s[j];
      acc0[j] *= a; acc1[j] *= a;
    }
    __syncthreads();

    // ---- row sums ----
    {
      const int l = t & 7, j = t >> 3;
      float p = 0.0f;
#pragma unroll 8
      for (int i = 0; i < MT / 8; ++i) p += Es[l + i * 8][j];
      p += __shfl_down(p, 4, 8);
      p += __shfl_down(p, 2, 8);
      p += __shfl_down(p, 1, 8);
      if (l == 0) red_s[j] = p;
    }
    __syncthreads();
    if (t < NT) S_s[t] = S_s[t] * A_s[t] + red_s[t];

    // ---- PV: acc[c][j] += V[m][c] * P[j][m] ----
    const unsigned short* vp = Vb + (size_t)m0 * C_ + t;
#pragma unroll 2
    for (int mm = 0; mm < MT; ++mm) {
      const float v0 = bf2f(vp[(size_t)mm * C_]);
      const float v1 = bf2f(vp[(size_t)mm * C_ + 256]);
#pragma unroll
      for (int jj = 0; jj < NT / 4; ++jj) {
        const float4 p4 = *(const float4*)&Es[mm][jj * 4];
        acc0[jj * 4 + 0] += v0 * p4.x; acc0[jj * 4 + 1] += v0 * p4.y;
        acc0[jj * 4 + 2] += v0 * p4.z; acc0[jj * 4 + 3] += v0 * p4.w;
        acc1[jj * 4 + 0] += v1 * p4.x; acc1[jj * 4 + 1] += v1 * p4.y;
        acc1[jj * 4 + 2] += v1 * p4.z; acc1[jj * 4 + 3] += v1 * p4.w;
      }
    }
    __syncthreads();  // protects Es/S_s for next tile
  }

  // ---- epilogue: out = gamma * (acc / S) + final_encoded ----
  const float g = gamma[0];
  float rs[NT];
#pragma unroll
  for (int j = 0; j < NT; ++j) rs[j] = 1.0f / S_s[j];

  float* outb      = out + (size_t)b * C_ * HW_ + n0;
  const float* feb = fe  + (size_t)b * C_ * HW_ + n0;
#pragma unroll
  for (int jj = 0; jj < NT / 4; ++jj) {
    float4 f0 = *(const float4*)&feb[(size_t)t * HW_ + jj * 4];
    float4 r0;
    r0.x = g * (acc0[jj * 4 + 0] * rs[jj * 4 + 0]) + f0.x;
    r0.y = g * (acc0[jj * 4 + 1] * rs[jj * 4 + 1]) + f0.y;
    r0.z = g * (acc0[jj * 4 + 2] * rs[jj * 4 + 2]) + f0.z;
    r0.w = g * (acc0[jj * 4 + 3] * rs[jj * 4 + 3]) + f0.w;
    *(float4*)&outb[(size_t)t * HW_ + jj * 4] = r0;

    float4 f1 = *(const float4*)&feb[(size_t)(t + 256) * HW_ + jj * 4];
    float4 r1;
    r1.x = g * (acc1[jj * 4 + 0] * rs[jj * 4 + 0]) + f1.x;
    r1.y = g * (acc1[jj * 4 + 1] * rs[jj * 4 + 1]) + f1.y;
    r1.z = g * (acc1[jj * 4 + 2] * rs[jj * 4 + 2]) + f1.z;
    r1.w = g * (acc1[jj * 4 + 3] * rs[jj * 4 + 3]) + f1.w;
    *(float4*)&outb[(size_t)(t + 256) * HW_ + jj * 4] = r1;
  }
}

// ---------------------------------------------------------------------------
extern "C" void kernel_launch(void* const* d_in, const int* in_sizes, int n_in,
                              void* d_out, int out_size, void* d_ws, size_t ws_size,
                              hipStream_t stream) {
  const float* fe    = (const float*)d_in[0];
  const float* total = (const float*)d_in[1];
  const float* Wq    = (const float*)d_in[2];
  const float* bq    = (const float*)d_in[3];
  const float* Wk    = (const float*)d_in[4];
  const float* bk    = (const float*)d_in[5];
  const float* Wv    = (const float*)d_in[6];
  const float* bv    = (const float*)d_in[7];
  const float* ht    = (const float*)d_in[8];
  const float* wt    = (const float*)d_in[9];
  const float* gamma = (const float*)d_in[10];
  float* out = (float*)d_out;

  // workspace layout: Qt (fp32, 4 MB) | Kp (fp32, 4 MB) | Vt (bf16, 16 MB)
  float* Qt = (float*)d_ws;
  float* Kp = Qt + (size_t)B_ * HW_ * C8_;
  unsigned short* Vt = (unsigned short*)(Kp + (size_t)B_ * C8_ * HW_);

  proj_t_kernel<false><<<dim3(HW_ / 64, 1, B_), 256, 0, stream>>>(total, Wq, bq, Qt, C8_);
  proj_k_kernel<<<dim3(HW_ / 64, B_), 256, 0, stream>>>(fe, Wk, bk, ht, wt, Kp);
  proj_t_kernel<true><<<dim3(HW_ / 64, C_ / 64, B_), 256, 0, stream>>>(fe, Wv, bv, Vt, C_);
  flash_kernel<<<dim3(HW_ / NT, B_), 256, 0, stream>>>(Qt, Kp, Vt, fe, gamma, out);
}

// Round 2
// 472.837 us; speedup vs baseline: 3.6297x; 3.6297x over previous
//
#include <hip/hip_runtime.h>
#include <hip/hip_bf16.h>

#define B_   4
#define C_   512
#define C8_  64
#define HW_  4096

typedef short bf16x8 __attribute__((ext_vector_type(8)));
typedef float f32x4  __attribute__((ext_vector_type(4)));

__device__ __forceinline__ unsigned short f2bf(float f) {
  union { unsigned int i; float f; } x; x.f = f;
  unsigned int r = x.i + 0x7fffu + ((x.i >> 16) & 1u);   // RNE
  return (unsigned short)(r >> 16);
}

#define MFMA(a, b, c) __builtin_amdgcn_mfma_f32_16x16x32_bf16((a), (b), (c), 0, 0, 0)

// ---------------------------------------------------------------------------
// proj_qk: which=0 -> Qh[m][o] = Wq.total + bq ; which=1 -> Kh[m][o] = Wk.fe +
// bk + ht[o][h] + wt[o][w]  (positional bias folded into K)
// grid (64, 2, 4), 256 thr. D[m][o]: M=m (A = X^T), N=o (B = W^T).
// ---------------------------------------------------------------------------
__global__ __launch_bounds__(256) void proj_qk_kernel(
    const float* __restrict__ total, const float* __restrict__ fe,
    const float* __restrict__ Wq, const float* __restrict__ bq,
    const float* __restrict__ Wk, const float* __restrict__ bk,
    const float* __restrict__ ht, const float* __restrict__ wt,
    unsigned short* __restrict__ Qh, unsigned short* __restrict__ Kh) {
  __shared__ __align__(16) unsigned short Xs[64 * 72];  // [m][c] pad 72
  __shared__ __align__(16) unsigned short Ws[64 * 72];  // [o][c] pad 72
  const int t = threadIdx.x;
  const int b = blockIdx.z;
  const int which = blockIdx.y;
  const int m0 = blockIdx.x * 64;
  const float* X = which ? fe : total;
  const float* W = which ? Wk : Wq;
  const float* bias = which ? bk : bq;
  unsigned short* dst = which ? Kh : Qh;
  const int lane = t & 63, w = t >> 6, ln = lane & 15, quad = lane >> 4;

  f32x4 acc[4];
#pragma unroll
  for (int i = 0; i < 4; ++i) acc[i] = f32x4{0.f, 0.f, 0.f, 0.f};

  for (int kb = 0; kb < 8; ++kb) {
    const int c0 = kb * 64;
#pragma unroll
    for (int i = 0; i < 4; ++i) {          // Ws: 64o x 64c
      int idx = t + i * 256; int o = idx >> 4, c4 = idx & 15;
      float4 wv = *(const float4*)&W[(size_t)o * C_ + c0 + c4 * 4];
      unsigned int p0 = f2bf(wv.x) | ((unsigned int)f2bf(wv.y) << 16);
      unsigned int p1 = f2bf(wv.z) | ((unsigned int)f2bf(wv.w) << 16);
      *(uint2*)&Ws[o * 72 + c4 * 4] = make_uint2(p0, p1);
    }
#pragma unroll
    for (int i = 0; i < 4; ++i) {          // Xs: transpose [c][m] -> [m][c]
      int idx = t + i * 256; int rc = idx >> 4, mq = idx & 15;
      float4 xv = *(const float4*)&X[((size_t)b * C_ + c0 + rc) * HW_ + m0 + mq * 4];
      Xs[(mq * 4 + 0) * 72 + rc] = f2bf(xv.x);
      Xs[(mq * 4 + 1) * 72 + rc] = f2bf(xv.y);
      Xs[(mq * 4 + 2) * 72 + rc] = f2bf(xv.z);
      Xs[(mq * 4 + 3) * 72 + rc] = f2bf(xv.w);
    }
    __syncthreads();
    bf16x8 a0 = *(const bf16x8*)&Xs[(w * 16 + ln) * 72 + quad * 8];
    bf16x8 a1 = *(const bf16x8*)&Xs[(w * 16 + ln) * 72 + 32 + quad * 8];
#pragma unroll
    for (int nt = 0; nt < 4; ++nt) {
      bf16x8 b0 = *(const bf16x8*)&Ws[(nt * 16 + ln) * 72 + quad * 8];
      bf16x8 b1 = *(const bf16x8*)&Ws[(nt * 16 + ln) * 72 + 32 + quad * 8];
      acc[nt] = MFMA(a0, b0, acc[nt]);
      acc[nt] = MFMA(a1, b1, acc[nt]);
    }
    __syncthreads();
  }

  const int h = m0 >> 6;   // m-tile of 64 == one image row
#pragma unroll
  for (int nt = 0; nt < 4; ++nt) {
    const int o = nt * 16 + ln;
    const float bz = bias[o];
    const float hv = which ? ht[o * 64 + h] : 0.0f;
#pragma unroll
    for (int r = 0; r < 4; ++r) {
      const int m = m0 + w * 16 + quad * 4 + r;
      float val = acc[nt][r] + bz + hv;
      if (which) val += wt[o * 64 + (m & 63)];
      dst[((size_t)b * HW_ + m) * 64 + o] = f2bf(val);
    }
  }
}

// ---------------------------------------------------------------------------
// proj_v: Vn[b][ch][m] = Wv.fe + bv (bf16). grid (64, 4, 4), 256 thr.
// D[ch][m]: M=ch (A = W), N=m (B = X). o-tile 128.
// ---------------------------------------------------------------------------
__global__ __launch_bounds__(256) void proj_v_kernel(
    const float* __restrict__ fe, const float* __restrict__ Wv,
    const float* __restrict__ bv, unsigned short* __restrict__ Vn) {
  __shared__ __align__(16) unsigned short Xs[64 * 72];    // [m][c]
  __shared__ __align__(16) unsigned short Ws[128 * 72];   // [o][c]
  const int t = threadIdx.x;
  const int b = blockIdx.z;
  const int o0 = blockIdx.y * 128;
  const int m0 = blockIdx.x * 64;
  const int lane = t & 63, w = t >> 6, ln = lane & 15, quad = lane >> 4;

  f32x4 acc[2][4];
#pragma unroll
  for (int p = 0; p < 2; ++p)
#pragma unroll
    for (int i = 0; i < 4; ++i) acc[p][i] = f32x4{0.f, 0.f, 0.f, 0.f};

  for (int kb = 0; kb < 8; ++kb) {
    const int c0 = kb * 64;
#pragma unroll
    for (int i = 0; i < 8; ++i) {          // Ws: 128o x 64c
      int idx = t + i * 256; int o = idx >> 4, c4 = idx & 15;
      float4 wv = *(const float4*)&Wv[(size_t)(o0 + o) * C_ + c0 + c4 * 4];
      unsigned int p0 = f2bf(wv.x) | ((unsigned int)f2bf(wv.y) << 16);
      unsigned int p1 = f2bf(wv.z) | ((unsigned int)f2bf(wv.w) << 16);
      *(uint2*)&Ws[o * 72 + c4 * 4] = make_uint2(p0, p1);
    }
#pragma unroll
    for (int i = 0; i < 4; ++i) {          // Xs transpose
      int idx = t + i * 256; int rc = idx >> 4, mq = idx & 15;
      float4 xv = *(const float4*)&fe[((size_t)b * C_ + c0 + rc) * HW_ + m0 + mq * 4];
      Xs[(mq * 4 + 0) * 72 + rc] = f2bf(xv.x);
      Xs[(mq * 4 + 1) * 72 + rc] = f2bf(xv.y);
      Xs[(mq * 4 + 2) * 72 + rc] = f2bf(xv.z);
      Xs[(mq * 4 + 3) * 72 + rc] = f2bf(xv.w);
    }
    __syncthreads();
    bf16x8 aW[2][2];
#pragma unroll
    for (int p = 0; p < 2; ++p) {
      aW[p][0] = *(const bf16x8*)&Ws[((w + 4 * p) * 16 + ln) * 72 + quad * 8];
      aW[p][1] = *(const bf16x8*)&Ws[((w + 4 * p) * 16 + ln) * 72 + 32 + quad * 8];
    }
#pragma unroll
    for (int nt = 0; nt < 4; ++nt) {
      bf16x8 b0 = *(const bf16x8*)&Xs[(nt * 16 + ln) * 72 + quad * 8];
      bf16x8 b1 = *(const bf16x8*)&Xs[(nt * 16 + ln) * 72 + 32 + quad * 8];
#pragma unroll
      for (int p = 0; p < 2; ++p) {
        acc[p][nt] = MFMA(aW[p][0], b0, acc[p][nt]);
        acc[p][nt] = MFMA(aW[p][1], b1, acc[p][nt]);
      }
    }
    __syncthreads();
  }

#pragma unroll
  for (int p = 0; p < 2; ++p) {
#pragma unroll
    for (int r = 0; r < 4; ++r) {
      const int ch = o0 + (w + 4 * p) * 16 + quad * 4 + r;
      const float bz = bv[ch];
#pragma unroll
      for (int nt = 0; nt < 4; ++nt) {
        const int m = m0 + nt * 16 + ln;
        Vn[((size_t)b * C_ + ch) * HW_ + m] = f2bf(acc[p][nt][r] + bz);
      }
    }
  }
}

// ---------------------------------------------------------------------------
// stats: exact softmax row max m and 1/s via MFMA QK^T (bit-identical E to
// the flash pass). grid (64, 4), 256 thr.
// ---------------------------------------------------------------------------
__global__ __launch_bounds__(256) void stats_kernel(
    const unsigned short* __restrict__ Qh, const unsigned short* __restrict__ Kh,
    float* __restrict__ mrow, float* __restrict__ rsrow) {
  __shared__ __align__(16) unsigned short Qs[64 * 72];
  __shared__ __align__(16) unsigned short Ks[64 * 72];
  const int t = threadIdx.x, b = blockIdx.y, q0 = blockIdx.x * 64;
  const int lane = t & 63, w = t >> 6, ln = lane & 15, quad = lane >> 4;

#pragma unroll
  for (int p = 0; p < 2; ++p) {
    int idx = t + p * 256; int row = idx >> 3, seg = idx & 7;
    *(uint4*)&Qs[row * 72 + seg * 8] =
        *(const uint4*)&Qh[((size_t)b * HW_ + q0 + row) * 64 + seg * 8];
  }
  __syncthreads();
  bf16x8 aq0 = *(const bf16x8*)&Qs[(w * 16 + ln) * 72 + quad * 8];
  bf16x8 aq1 = *(const bf16x8*)&Qs[(w * 16 + ln) * 72 + 32 + quad * 8];

  float mr[4] = {-3e38f, -3e38f, -3e38f, -3e38f};
  float sr[4] = {0.f, 0.f, 0.f, 0.f};

  for (int kt = 0; kt < 64; ++kt) {
    const int mk = kt * 64;
    __syncthreads();
#pragma unroll
    for (int p = 0; p < 2; ++p) {
      int idx = t + p * 256; int row = idx >> 3, seg = idx & 7;
      *(uint4*)&Ks[row * 72 + seg * 8] =
          *(const uint4*)&Kh[((size_t)b * HW_ + mk + row) * 64 + seg * 8];
    }
    __syncthreads();
    f32x4 e[4];
#pragma unroll
    for (int nt = 0; nt < 4; ++nt) {
      e[nt] = f32x4{0.f, 0.f, 0.f, 0.f};
      bf16x8 b0 = *(const bf16x8*)&Ks[(nt * 16 + ln) * 72 + quad * 8];
      bf16x8 b1 = *(const bf16x8*)&Ks[(nt * 16 + ln) * 72 + 32 + quad * 8];
      e[nt] = MFMA(aq0, b0, e[nt]);
      e[nt] = MFMA(aq1, b1, e[nt]);
    }
#pragma unroll
    for (int r = 0; r < 4; ++r) {
      float v = fmaxf(fmaxf(e[0][r], e[1][r]), fmaxf(e[2][r], e[3][r]));
      v = fmaxf(v, __shfl_xor(v, 1, 16));
      v = fmaxf(v, __shfl_xor(v, 2, 16));
      v = fmaxf(v, __shfl_xor(v, 4, 16));
      v = fmaxf(v, __shfl_xor(v, 8, 16));
      const float mn = fmaxf(mr[r], v);
      const float al = __expf(mr[r] - mn);
      float s = __expf(e[0][r] - mn) + __expf(e[1][r] - mn) +
                __expf(e[2][r] - mn) + __expf(e[3][r] - mn);
      s += __shfl_xor(s, 1, 16);
      s += __shfl_xor(s, 2, 16);
      s += __shfl_xor(s, 4, 16);
      s += __shfl_xor(s, 8, 16);
      sr[r] = sr[r] * al + s;
      mr[r] = mn;
    }
  }
  if (ln == 0) {
#pragma unroll
    for (int r = 0; r < 4; ++r) {
      const int q = q0 + w * 16 + quad * 4 + r;
      mrow[(size_t)b * HW_ + q] = mr[r];
      rsrow[(size_t)b * HW_ + q] = 1.0f / sr[r];
    }
  }
}

// ---------------------------------------------------------------------------
// flash pass 2: P = exp(E - m), O = P.V (MFMA, output-transposed D[ch][q]),
// epilogue out = gamma*O*rs + fe. grid (256), 512 thr (8 waves).
// Block->(b,q0) swizzle: XCD x serves only batch x&3 (V slice = 4MB = L2).
// ---------------------------------------------------------------------------
__global__ __launch_bounds__(512) void flash_kernel(
    const unsigned short* __restrict__ Qh, const unsigned short* __restrict__ Kh,
    const unsigned short* __restrict__ Vn, const float* __restrict__ mrow,
    const float* __restrict__ rsrow, const float* __restrict__ fe,
    const float* __restrict__ gamma, float* __restrict__ out) {
  __shared__ __align__(16) unsigned short Qs[64 * 72];   // [q][c]
  __shared__ __align__(16) unsigned short Ks[32 * 72];   // [key][c]
  __shared__ __align__(16) unsigned short Ps[64 * 40];   // [q][key] pad 40
  __shared__ __align__(16) unsigned short Vs[512 * 40];  // [ch][key] pad 40
  __shared__ float Sm[64], Srs[64];

  const int t = threadIdx.x;
  const int n = blockIdx.x;
  const int xcd = n & 7, j = n >> 3;
  const int b = xcd & 3;
  const int q0 = (j * 2 + (xcd >> 2)) * 64;
  const int lane = t & 63, w = t >> 6, ln = lane & 15, quad = lane >> 4;

  { int row = t >> 3, seg = t & 7;
    *(uint4*)&Qs[row * 72 + seg * 8] =
        *(const uint4*)&Qh[((size_t)b * HW_ + q0 + row) * 64 + seg * 8]; }
  if (t < 64) {
    Sm[t]  = mrow [(size_t)b * HW_ + q0 + t];
    Srs[t] = rsrow[(size_t)b * HW_ + q0 + t];
  }
  __syncthreads();

  const int mt_q = w >> 1, nt_k = w & 1;
  bf16x8 aq0 = *(const bf16x8*)&Qs[(mt_q * 16 + ln) * 72 + quad * 8];
  bf16x8 aq1 = *(const bf16x8*)&Qs[(mt_q * 16 + ln) * 72 + 32 + quad * 8];

  f32x4 acc[4][4];
#pragma unroll
  for (int mt = 0; mt < 4; ++mt)
#pragma unroll
    for (int nt = 0; nt < 4; ++nt) acc[mt][nt] = f32x4{0.f, 0.f, 0.f, 0.f};

  const size_t vbase = (size_t)b * C_ * HW_;

  for (int kt = 0; kt < 128; ++kt) {
    const int mk = kt * 32;
#pragma unroll
    for (int p = 0; p < 4; ++p) {          // Vs: 512ch x 32keys
      int idx = t + p * 512; int ch = idx >> 2, seg = idx & 3;
      *(uint4*)&Vs[ch * 40 + seg * 8] =
          *(const uint4*)&Vn[vbase + (size_t)ch * HW_ + mk + seg * 8];
    }
    if (t < 256) {                         // Ks: 32keys x 64c
      int row = t >> 3, seg = t & 7;
      *(uint4*)&Ks[row * 72 + seg * 8] =
          *(const uint4*)&Kh[((size_t)b * HW_ + mk + row) * 64 + seg * 8];
    }
    __syncthreads();

    f32x4 e = f32x4{0.f, 0.f, 0.f, 0.f};
    bf16x8 kb0 = *(const bf16x8*)&Ks[(nt_k * 16 + ln) * 72 + quad * 8];
    bf16x8 kb1 = *(const bf16x8*)&Ks[(nt_k * 16 + ln) * 72 + 32 + quad * 8];
    e = MFMA(aq0, kb0, e);
    e = MFMA(aq1, kb1, e);
#pragma unroll
    for (int r = 0; r < 4; ++r) {
      const int q = mt_q * 16 + quad * 4 + r;
      const float p = __expf(e[r] - Sm[q]);
      Ps[q * 40 + nt_k * 16 + ln] = f2bf(p);
    }
    __syncthreads();

    bf16x8 av[4], bp[4];
#pragma unroll
    for (int mt = 0; mt < 4; ++mt)
      av[mt] = *(const bf16x8*)&Vs[(w * 64 + mt * 16 + ln) * 40 + quad * 8];
#pragma unroll
    for (int nt = 0; nt < 4; ++nt)
      bp[nt] = *(const bf16x8*)&Ps[(nt * 16 + ln) * 40 + quad * 8];
#pragma unroll
    for (int mt = 0; mt < 4; ++mt)
#pragma unroll
      for (int nt = 0; nt < 4; ++nt)
        acc[mt][nt] = MFMA(av[mt], bp[nt], acc[mt][nt]);
    __syncthreads();
  }

  const float g = gamma[0];
#pragma unroll
  for (int nt = 0; nt < 4; ++nt) {
    const float rsv = Srs[nt * 16 + ln];
#pragma unroll
    for (int mt = 0; mt < 4; ++mt) {
#pragma unroll
      for (int r = 0; r < 4; ++r) {
        const int ch = w * 64 + mt * 16 + quad * 4 + r;
        const size_t idx = ((size_t)b * C_ + ch) * HW_ + q0 + nt * 16 + ln;
        out[idx] = g * (acc[mt][nt][r] * rsv) + fe[idx];
      }
    }
  }
}

// ---------------------------------------------------------------------------
extern "C" void kernel_launch(void* const* d_in, const int* in_sizes, int n_in,
                              void* d_out, int out_size, void* d_ws, size_t ws_size,
                              hipStream_t stream) {
  const float* fe    = (const float*)d_in[0];
  const float* total = (const float*)d_in[1];
  const float* Wq    = (const float*)d_in[2];
  const float* bq    = (const float*)d_in[3];
  const float* Wk    = (const float*)d_in[4];
  const float* bk    = (const float*)d_in[5];
  const float* Wv    = (const float*)d_in[6];
  const float* bv    = (const float*)d_in[7];
  const float* ht    = (const float*)d_in[8];
  const float* wt    = (const float*)d_in[9];
  const float* gamma = (const float*)d_in[10];
  float* out = (float*)d_out;

  // ws: Qh 2MB | Kh 2MB | Vn 16MB | mrow 64KB | rsrow 64KB  (20.1 MB total)
  unsigned short* Qh = (unsigned short*)d_ws;
  unsigned short* Kh = Qh + (size_t)B_ * HW_ * C8_;
  unsigned short* Vn = Kh + (size_t)B_ * HW_ * C8_;
  float* mrow  = (float*)(Vn + (size_t)B_ * C_ * HW_);
  float* rsrow = mrow + (size_t)B_ * HW_;

  proj_qk_kernel<<<dim3(64, 2, B_), 256, 0, stream>>>(total, fe, Wq, bq, Wk, bk,
                                                      ht, wt, Qh, Kh);
  proj_v_kernel<<<dim3(64, 4, B_), 256, 0, stream>>>(fe, Wv, bv, Vn);
  stats_kernel<<<dim3(64, B_), 256, 0, stream>>>(Qh, Kh, mrow, rsrow);
  flash_kernel<<<dim3(256), 512, 0, stream>>>(Qh, Kh, Vn, mrow, rsrow, fe, gamma, out);
}